// Round 1
// baseline (1181.523 us; speedup 1.0000x reference)
//
#include <hip/hip_runtime.h>
#include <math.h>

#define NSPK 2048
#define GUT  10
#define DIM  512
#define NG   (NSPK*GUT)

#define ROWS 32
#define MT   256
#define KC   64

// ---------------- Kernel 1: per-speaker prep ----------------
// Computes, per speaker n: centroid (normalized -> cn), per-utterance
// normalized embeddings (xn), and the exclusion-centroid cosine (diag)
// via the algebraic identities (no exc materialization).
__global__ __launch_bounds__(256) void k1_prep(const float* __restrict__ x,
    float* __restrict__ xn, float* __restrict__ cn, float* __restrict__ diag)
{
  const int n = blockIdx.x;
  const int t = threadIdx.x;
  const float* xb = x + (size_t)n * GUT * DIM + 2 * t;

  float2 xv[GUT];
#pragma unroll
  for (int g = 0; g < GUT; ++g)
    xv[g] = *reinterpret_cast<const float2*>(xb + g * DIM);

  float sx = 0.f, sy = 0.f;
#pragma unroll
  for (int g = 0; g < GUT; ++g) { sx += xv[g].x; sy += xv[g].y; }

  float part[21];
#pragma unroll
  for (int g = 0; g < GUT; ++g) {
    part[g]      = xv[g].x * xv[g].x + xv[g].y * xv[g].y;  // ||x_g||^2 partial
    part[10 + g] = xv[g].x * sx + xv[g].y * sy;            // dot(x_g, sum) partial
  }
  part[20] = sx * sx + sy * sy;                            // ||sum||^2 partial

  __shared__ float wred[21][4];
  __shared__ float res[21];
  const int lane = t & 63, wid = t >> 6;
#pragma unroll
  for (int q = 0; q < 21; ++q) {
    float v = part[q];
    for (int off = 32; off > 0; off >>= 1) v += __shfl_down(v, off);
    if (lane == 0) wred[q][wid] = v;
  }
  __syncthreads();
  if (t < 21) res[t] = wred[t][0] + wred[t][1] + wred[t][2] + wred[t][3];
  __syncthreads();

  const float psum = res[20];
  const float cnorm = sqrtf(psum) * (1.0f / GUT);          // ||centroid||
  const float cscale = (1.0f / GUT) / fmaxf(cnorm, 1e-8f);
  reinterpret_cast<float2*>(cn + (size_t)n * DIM)[t] = make_float2(sx * cscale, sy * cscale);

#pragma unroll
  for (int g = 0; g < GUT; ++g) {
    const float nx = sqrtf(res[g]);
    const float sc = 1.0f / fmaxf(nx, 1e-8f);
    reinterpret_cast<float2*>(xn + ((size_t)(n * GUT + g)) * DIM)[t] =
        make_float2(xv[g].x * sc, xv[g].y * sc);
  }

  if (t < GUT) {
    const int g = t;
    const float psq = res[g], pd = res[10 + g];
    const float dxe = (pd - psq) * (1.0f / (GUT - 1));
    float ne2 = (psum - 2.f * pd + psq) * (1.0f / ((GUT - 1) * (GUT - 1)));
    ne2 = fmaxf(ne2, 0.f);
    const float dnm = fmaxf(sqrtf(psq), 1e-8f) * fmaxf(sqrtf(ne2), 1e-8f);
    diag[n * GUT + g] = dxe / dnm;
  }
}

// ---------------- Kernel 2: fused sim-GEMM + online log-softmax ----------------
// Each block: 32 full rows (n,g), sweep all 2048 centroids in 256-col tiles.
// Online softmax / argmax / target capture in registers, lane-merge at end.
__global__ __launch_bounds__(256) void k2_simloss(
    const float* __restrict__ xn, const float* __restrict__ cn,
    const float* __restrict__ diag, const float* __restrict__ wp,
    const float* __restrict__ bp,
    float* __restrict__ row_logp, float* __restrict__ row_corr)
{
  __shared__ float As[ROWS][516];   // pad 512->516 (16B-aligned rows)
  __shared__ float Bs[MT][68];      // pad 64->68  (16B-aligned rows)
  const int tid = threadIdx.x;
  const int rowbase = blockIdx.x * ROWS;
  const float wv = wp[0], bv = bp[0];
  const int tr = tid >> 5, tc = tid & 31;

  // Stage A panel (32x512 contiguous) once.
  {
    const float4* src = reinterpret_cast<const float4*>(xn + (size_t)rowbase * DIM);
#pragma unroll
    for (int u = 0; u < 16; ++u) {
      const int idx = tid + 256 * u;
      float4 v = src[idx];
      *reinterpret_cast<float4*>(&As[idx >> 7][(idx & 127) * 4]) = v;
    }
  }

  int nIdx[4]; float dg[4];
#pragma unroll
  for (int i = 0; i < 4; ++i) {
    const int row = rowbase + tr + 8 * i;
    nIdx[i] = row / GUT;
    dg[i] = diag[row];
  }
  float mx[4], se[4], bestv[4], tgt[4]; int besti[4];
#pragma unroll
  for (int i = 0; i < 4; ++i) {
    mx[i] = -__builtin_inff(); se[i] = 0.f;
    bestv[i] = -__builtin_inff(); tgt[i] = -__builtin_inff();
    besti[i] = 0x7fffffff;
  }

  for (int mt = 0; mt < NSPK / MT; ++mt) {
    float acc[4][8];
#pragma unroll
    for (int i = 0; i < 4; ++i)
#pragma unroll
      for (int j = 0; j < 8; ++j) acc[i][j] = 0.f;

    for (int kc = 0; kc < DIM / KC; ++kc) {
      __syncthreads();
      {
        const float* bsrc = cn + (size_t)mt * MT * DIM + kc * KC;
#pragma unroll
        for (int u = 0; u < 16; ++u) {
          const int idx = tid + 256 * u;
          const int c = idx >> 4, fc = idx & 15;
          float4 v = *reinterpret_cast<const float4*>(bsrc + (size_t)c * DIM + fc * 4);
          *reinterpret_cast<float4*>(&Bs[c][fc * 4]) = v;
        }
      }
      __syncthreads();
#pragma unroll 4
      for (int k4 = 0; k4 < KC; k4 += 4) {
        float4 a[4], bq[8];
#pragma unroll
        for (int i = 0; i < 4; ++i)
          a[i] = *reinterpret_cast<const float4*>(&As[tr + 8 * i][kc * KC + k4]);
#pragma unroll
        for (int j = 0; j < 8; ++j)
          bq[j] = *reinterpret_cast<const float4*>(&Bs[tc + 32 * j][k4]);
#pragma unroll
        for (int i = 0; i < 4; ++i)
#pragma unroll
          for (int j = 0; j < 8; ++j) {
            acc[i][j] += a[i].x * bq[j].x;
            acc[i][j] += a[i].y * bq[j].y;
            acc[i][j] += a[i].z * bq[j].z;
            acc[i][j] += a[i].w * bq[j].w;
          }
      }
    }
    // Epilogue for this m-tile: replace diag, clamp, logit, online update.
#pragma unroll
    for (int i = 0; i < 4; ++i) {
#pragma unroll
      for (int j = 0; j < 8; ++j) {
        const int m = mt * MT + tc + 32 * j;
        float s = acc[i][j];
        if (m == nIdx[i]) s = dg[i];
        s = fmaxf(s, 1e-6f);
        const float L = fmaf(s, wv, bv);
        if (m == nIdx[i]) tgt[i] = L;
        if (L > bestv[i]) { bestv[i] = L; besti[i] = m; }   // ascending m: strict > keeps first index
        if (L > mx[i]) { se[i] = se[i] * __expf(mx[i] - L) + 1.0f; mx[i] = L; }
        else            se[i] += __expf(L - mx[i]);
      }
    }
  }

  // Merge the 32 lanes (tc) sharing each row: online-softmax merge + argmax + target.
#pragma unroll
  for (int i = 0; i < 4; ++i) {
    for (int off = 16; off > 0; off >>= 1) {
      const float omx = __shfl_xor(mx[i], off);
      const float ose = __shfl_xor(se[i], off);
      const float obv = __shfl_xor(bestv[i], off);
      const int   obi = __shfl_xor(besti[i], off);
      const float otg = __shfl_xor(tgt[i], off);
      const float nm = fmaxf(mx[i], omx);
      se[i] = se[i] * __expf(mx[i] - nm) + ose * __expf(omx - nm);
      mx[i] = nm;
      if (obv > bestv[i] || (obv == bestv[i] && obi < besti[i])) { bestv[i] = obv; besti[i] = obi; }
      tgt[i] = fmaxf(tgt[i], otg);
    }
    if (tc == 0) {
      const int row = rowbase + tr + 8 * i;
      row_logp[row] = tgt[i] - mx[i] - logf(se[i]);
      row_corr[row] = (besti[i] == nIdx[i]) ? 1.0f : 0.0f;
    }
  }
}

// ---------------- Kernel 3: final scalar reduction ----------------
__global__ __launch_bounds__(256) void k3_reduce(const float* __restrict__ row_logp,
    const float* __restrict__ row_corr, float* __restrict__ out)
{
  const int t = threadIdx.x;
  float sl = 0.f, sc = 0.f;
  for (int i = t; i < NG; i += 256) { sl += row_logp[i]; sc += row_corr[i]; }
  for (int off = 32; off > 0; off >>= 1) { sl += __shfl_down(sl, off); sc += __shfl_down(sc, off); }
  __shared__ float ra[4], rb[4];
  const int lane = t & 63, wid = t >> 6;
  if (lane == 0) { ra[wid] = sl; rb[wid] = sc; }
  __syncthreads();
  if (t == 0) {
    const float S = ra[0] + ra[1] + ra[2] + ra[3];
    const float C = rb[0] + rb[1] + rb[2] + rb[3];
    out[0] = -(S * (1.0f / NG));
    out[1] = C * (100.0f / NG);
  }
}

extern "C" void kernel_launch(void* const* d_in, const int* in_sizes, int n_in,
                              void* d_out, int out_size, void* d_ws, size_t ws_size,
                              hipStream_t stream)
{
  const float* x = (const float*)d_in[0];
  const float* w = (const float*)d_in[1];
  const float* b = (const float*)d_in[2];
  float* out = (float*)d_out;

  float* ws   = (float*)d_ws;
  float* xn   = ws;                            // 20480*512
  float* cn   = xn + (size_t)NG * DIM;         // 2048*512
  float* diag = cn + (size_t)NSPK * DIM;       // 20480
  float* rlp  = diag + NG;                     // 20480
  float* rcr  = rlp + NG;                      // 20480

  hipLaunchKernelGGL(k1_prep,   dim3(NSPK),      dim3(256), 0, stream, x, xn, cn, diag);
  hipLaunchKernelGGL(k2_simloss, dim3(NG / ROWS), dim3(256), 0, stream, xn, cn, diag, w, b, rlp, rcr);
  hipLaunchKernelGGL(k3_reduce, dim3(1),         dim3(256), 0, stream, rlp, rcr, out);
}

// Round 3
// 246.305 us; speedup vs baseline: 4.7970x; 4.7970x over previous
//
#include <hip/hip_runtime.h>
#include <math.h>

#define NSPK 2048
#define GUT  10
#define DIM  512
#define NG   (NSPK*GUT)

#define BM 128
#define BN 128
#define BK 64
#define NCB (NSPK/BN)   // 16 column blocks
#define NHB (NCB*2)     // 32 column half-blocks (64 cols each) -- one per wave
#define NRB (NG/BM)     // 160 row blocks

typedef __attribute__((ext_vector_type(8))) short short8;
typedef __attribute__((ext_vector_type(4))) float f32x4;

__device__ inline unsigned short f2bf(float f) {
  unsigned u = __float_as_uint(f);
  return (unsigned short)((u + 0x7FFFu + ((u >> 16) & 1u)) >> 16);   // RNE
}
__device__ inline float bf2f(unsigned short h) {
  return __uint_as_float(((unsigned)h) << 16);
}
__device__ inline void gload_lds16(const void* g, void* l) {
  __builtin_amdgcn_global_load_lds(
      (const __attribute__((address_space(1))) void*)g,
      (__attribute__((address_space(3))) void*)l, 16, 0, 0);
}

// ---------------- Kernel 1: per-speaker prep (+ bf16 hi/lo emit) ----------------
__global__ __launch_bounds__(256) void k1_prep(const float* __restrict__ x,
    unsigned* __restrict__ xn_hi, unsigned* __restrict__ xn_lo,
    unsigned* __restrict__ cn_hi, unsigned* __restrict__ cn_lo,
    float* __restrict__ diag)
{
  const int n = blockIdx.x;
  const int t = threadIdx.x;
  const float* xb = x + (size_t)n * GUT * DIM + 2 * t;

  float2 xv[GUT];
#pragma unroll
  for (int g = 0; g < GUT; ++g)
    xv[g] = *reinterpret_cast<const float2*>(xb + g * DIM);

  float sx = 0.f, sy = 0.f;
#pragma unroll
  for (int g = 0; g < GUT; ++g) { sx += xv[g].x; sy += xv[g].y; }

  float part[21];
#pragma unroll
  for (int g = 0; g < GUT; ++g) {
    part[g]      = xv[g].x * xv[g].x + xv[g].y * xv[g].y;
    part[10 + g] = xv[g].x * sx + xv[g].y * sy;
  }
  part[20] = sx * sx + sy * sy;

  __shared__ float wred[21][4];
  __shared__ float res[21];
  const int lane = t & 63, wid = t >> 6;
#pragma unroll
  for (int q = 0; q < 21; ++q) {
    float v = part[q];
    for (int off = 32; off > 0; off >>= 1) v += __shfl_down(v, off);
    if (lane == 0) wred[q][wid] = v;
  }
  __syncthreads();
  if (t < 21) res[t] = wred[t][0] + wred[t][1] + wred[t][2] + wred[t][3];
  __syncthreads();

  const float psum = res[20];
  const float cnorm = sqrtf(psum) * (1.0f / GUT);
  const float cscale = (1.0f / GUT) / fmaxf(cnorm, 1e-8f);
  {
    const float cx = sx * cscale, cy = sy * cscale;
    const unsigned short hx = f2bf(cx), hy = f2bf(cy);
    const unsigned short lx = f2bf(cx - bf2f(hx)), ly = f2bf(cy - bf2f(hy));
    cn_hi[n * (DIM / 2) + t] = ((unsigned)hy << 16) | hx;
    cn_lo[n * (DIM / 2) + t] = ((unsigned)ly << 16) | lx;
  }

#pragma unroll
  for (int g = 0; g < GUT; ++g) {
    const float nx = sqrtf(res[g]);
    const float sc = 1.0f / fmaxf(nx, 1e-8f);
    const float vx = xv[g].x * sc, vy = xv[g].y * sc;
    const unsigned short hx = f2bf(vx), hy = f2bf(vy);
    const unsigned short lx = f2bf(vx - bf2f(hx)), ly = f2bf(vy - bf2f(hy));
    const size_t row = (size_t)n * GUT + g;
    xn_hi[row * (DIM / 2) + t] = ((unsigned)hy << 16) | hx;
    xn_lo[row * (DIM / 2) + t] = ((unsigned)ly << 16) | lx;
  }

  if (t < GUT) {
    const int g = t;
    const float psq = res[g], pd = res[10 + g];
    const float dxe = (pd - psq) * (1.0f / (GUT - 1));
    float ne2 = (psum - 2.f * pd + psq) * (1.0f / ((GUT - 1) * (GUT - 1)));
    ne2 = fmaxf(ne2, 0.f);
    const float dnm = fmaxf(sqrtf(psq), 1e-8f) * fmaxf(sqrtf(ne2), 1e-8f);
    diag[n * GUT + g] = dxe / dnm;
  }
}

// ---------------- Kernel 2: split-bf16 MFMA GEMM + fused online softmax ----------------
// Grid: 160 rowblocks x 16 colblocks. Block: 256 thr = 4 waves, each wave 64x64 out.
// LDS: Ah,Al,Bh,Bl tiles [128][64] bf16, XOR-swizzled (byte ^= (row&7)<<4).
// Partials are per (row, 64-col half-block): NO two waves share a slot.
__global__ __launch_bounds__(256) void k2_mfma(
    const unsigned short* __restrict__ xn_hi, const unsigned short* __restrict__ xn_lo,
    const unsigned short* __restrict__ cn_hi, const unsigned short* __restrict__ cn_lo,
    const float* __restrict__ diag, const float* __restrict__ wp,
    const float* __restrict__ bp, float* __restrict__ partial)
{
  __shared__ short lds[4 * BM * BK];          // 64 KB
  char* ldsb = (char*)lds;
  const int AH = 0, AL = 16384, BH = 32768, BL = 49152;

  const int tid = threadIdx.x;
  const int l = tid & 63, w = tid >> 6;
  const int rb = blockIdx.x >> 4, cb = blockIdx.x & 15;
  const int rowbase = rb * BM, colbase = cb * BN;

  f32x4 acc[4][4];
#pragma unroll
  for (int i = 0; i < 4; ++i)
#pragma unroll
    for (int j = 0; j < 4; ++j)
#pragma unroll
      for (int e = 0; e < 4; ++e) acc[i][j][e] = 0.f;

  // Staging geometry: instr i covers LDS rows i*8..i*8+7; lane l -> row i*8+(l>>3),
  // 16B chunk (l&7). Pre-swizzled global source chunk = (l&7)^(l>>3)  [rule 21].
  const int sR = l >> 3;                       // 0..7
  const int sC = (l & 7) ^ sR;                 // source chunk index
  const int srcColElem = sC * 8;               // element offset within 64-elem k-slab

  // Fragment-read geometry: row R = 16*mf + (l&15) (+wave offset), R&7 == l&7.
  const int wr = w >> 1, wc = w & 1;
  const int lr = l & 15, lq = l >> 4, axor = l & 7;
  int aOff[4], bOff[4];
#pragma unroll
  for (int f = 0; f < 4; ++f) {
    aOff[f] = (wr * 64 + f * 16 + lr) * 128;   // byte offset of row
    bOff[f] = (wc * 64 + f * 16 + lr) * 128;
  }

  for (int kc = 0; kc < DIM / BK; ++kc) {
    __syncthreads();
    // ---- stage 4 tiles (each wave: 4 instrs per component) ----
#pragma unroll
    for (int q = 0; q < 4; ++q) {
      const int i = w * 4 + q;
      const size_t aoff = (size_t)(rowbase + i * 8 + sR) * DIM + kc * BK + srcColElem;
      const size_t boff = (size_t)(colbase + i * 8 + sR) * DIM + kc * BK + srcColElem;
      gload_lds16(xn_hi + aoff, ldsb + AH + i * 1024);
      gload_lds16(xn_lo + aoff, ldsb + AL + i * 1024);
      gload_lds16(cn_hi + boff, ldsb + BH + i * 1024);
      gload_lds16(cn_lo + boff, ldsb + BL + i * 1024);
    }
    __syncthreads();

    // ---- compute: 2 x (K=32) steps, 4x4 frags, 3 products each ----
#pragma unroll
    for (int kk = 0; kk < 2; ++kk) {
      const int coff = ((kk * 4 + lq) ^ axor) * 16;
      short8 ah[4], al4[4], bh[4], bl4[4];
#pragma unroll
      for (int f = 0; f < 4; ++f) {
        ah[f]  = *reinterpret_cast<const short8*>(ldsb + AH + aOff[f] + coff);
        al4[f] = *reinterpret_cast<const short8*>(ldsb + AL + aOff[f] + coff);
        bh[f]  = *reinterpret_cast<const short8*>(ldsb + BH + bOff[f] + coff);
        bl4[f] = *reinterpret_cast<const short8*>(ldsb + BL + bOff[f] + coff);
      }
#pragma unroll
      for (int mf = 0; mf < 4; ++mf)
#pragma unroll
        for (int nf = 0; nf < 4; ++nf) {
          acc[mf][nf] = __builtin_amdgcn_mfma_f32_16x16x32_bf16(ah[mf], bh[nf], acc[mf][nf], 0, 0, 0);
          acc[mf][nf] = __builtin_amdgcn_mfma_f32_16x16x32_bf16(ah[mf], bl4[nf], acc[mf][nf], 0, 0, 0);
          acc[mf][nf] = __builtin_amdgcn_mfma_f32_16x16x32_bf16(al4[mf], bh[nf], acc[mf][nf], 0, 0, 0);
        }
    }
  }

  // ---- epilogue: C/D layout col=lane&15, row=(lane>>4)*4+reg ----
  const float wv = wp[0], bv = bp[0];
#pragma unroll
  for (int mf = 0; mf < 4; ++mf) {
#pragma unroll
    for (int r = 0; r < 4; ++r) {
      const int row = rowbase + wr * 64 + mf * 16 + lq * 4 + r;
      const int n = row / GUT;
      const int tcol = n - colbase;                      // target col, local to 128-block
      const float dval = (tcol >= 0 && tcol < BN) ? diag[row] : 0.f;
      float mx = -__builtin_inff(), se = 0.f;
      float bvv = -__builtin_inff(), tg = -__builtin_inff();
      int bi = 0x7fffffff;
#pragma unroll
      for (int nf = 0; nf < 4; ++nf) {
        const int coll = wc * 64 + nf * 16 + lr;
        float s = acc[mf][nf][r];
        if (coll == tcol) s = dval;
        s = fmaxf(s, 1e-6f);
        const float L = fmaf(s, wv, bv);
        if (coll == tcol) tg = L;
        if (L > bvv) { bvv = L; bi = colbase + coll; }
        if (L > mx) { se = se * __expf(mx - L) + 1.0f; mx = L; }
        else          se += __expf(L - mx);
      }
#pragma unroll
      for (int off = 1; off < 16; off <<= 1) {
        const float omx = __shfl_xor(mx, off);
        const float ose = __shfl_xor(se, off);
        const float obv = __shfl_xor(bvv, off);
        const int   obi = __shfl_xor(bi, off);
        const float otg = __shfl_xor(tg, off);
        const float nm = fmaxf(mx, omx);
        se = se * __expf(mx - nm) + ose * __expf(omx - nm);
        mx = nm;
        if (obv > bvv || (obv == bvv && obi < bi)) { bvv = obv; bi = obi; }
        tg = fmaxf(tg, otg);
      }
      if (lr == 0) {
        // one slot per (row, 64-col half): half index = cb*2 + wc  -- no cross-wave race
        float* p = partial + ((size_t)row * NHB + cb * 2 + wc) * 5;
        p[0] = mx; p[1] = se; p[2] = bvv; p[3] = __int_as_float(bi); p[4] = tg;
      }
    }
  }
}

// ---------------- Kernel 3: merge 32 half-block partials per row ----------------
__global__ __launch_bounds__(256) void k3_rows(const float* __restrict__ partial,
    float* __restrict__ rlp, float* __restrict__ rcr)
{
  const int row = blockIdx.x * 256 + threadIdx.x;
  const float* p = partial + (size_t)row * NHB * 5;
  float mx = -__builtin_inff(), se = 0.f, bv = -__builtin_inff(), tg = -__builtin_inff();
  int bi = 0x7fffffff;
#pragma unroll
  for (int c = 0; c < NHB; ++c) {
    const float m2 = p[c * 5 + 0], s2 = p[c * 5 + 1], b2 = p[c * 5 + 2];
    const int   i2 = __float_as_int(p[c * 5 + 3]);
    const float t2 = p[c * 5 + 4];
    const float nm = fmaxf(mx, m2);
    se = se * __expf(mx - nm) + s2 * __expf(m2 - nm);
    mx = nm;
    if (b2 > bv || (b2 == bv && i2 < bi)) { bv = b2; bi = i2; }
    tg = fmaxf(tg, t2);
  }
  rlp[row] = tg - mx - logf(se);
  rcr[row] = (bi == row / GUT) ? 1.0f : 0.0f;
}

// ---------------- Kernel 4: final scalar reduction ----------------
__global__ __launch_bounds__(256) void k4_reduce(const float* __restrict__ row_logp,
    const float* __restrict__ row_corr, float* __restrict__ out)
{
  const int t = threadIdx.x;
  float sl = 0.f, sc = 0.f;
  for (int i = t; i < NG; i += 256) { sl += row_logp[i]; sc += row_corr[i]; }
  for (int off = 32; off > 0; off >>= 1) { sl += __shfl_down(sl, off); sc += __shfl_down(sc, off); }
  __shared__ float ra[4], rb2[4];
  const int lane = t & 63, wid = t >> 6;
  if (lane == 0) { ra[wid] = sl; rb2[wid] = sc; }
  __syncthreads();
  if (t == 0) {
    const float S = ra[0] + ra[1] + ra[2] + ra[3];
    const float C = rb2[0] + rb2[1] + rb2[2] + rb2[3];
    out[0] = -(S * (1.0f / NG));
    out[1] = C * (100.0f / NG);
  }
}

extern "C" void kernel_launch(void* const* d_in, const int* in_sizes, int n_in,
                              void* d_out, int out_size, void* d_ws, size_t ws_size,
                              hipStream_t stream)
{
  const float* x = (const float*)d_in[0];
  const float* w = (const float*)d_in[1];
  const float* b = (const float*)d_in[2];
  float* out = (float*)d_out;

  char* ws = (char*)d_ws;
  unsigned* xn_hi = (unsigned*)ws;                                   // 20480*512*2B
  unsigned* xn_lo = (unsigned*)(ws + (size_t)NG * DIM * 2);          // 20480*512*2B
  unsigned* cn_hi = (unsigned*)(ws + (size_t)NG * DIM * 4);          // 2048*512*2B
  unsigned* cn_lo = (unsigned*)(ws + (size_t)NG * DIM * 4 + (size_t)NSPK * DIM * 2);
  char* after = ws + (size_t)NG * DIM * 4 + (size_t)NSPK * DIM * 4;
  float* diag = (float*)after;                                       // 20480
  float* part = diag + NG;                                           // 20480*32*5
  float* rlp  = part + (size_t)NG * NHB * 5;                         // 20480
  float* rcr  = rlp + NG;                                            // 20480

  hipLaunchKernelGGL(k1_prep, dim3(NSPK), dim3(256), 0, stream,
                     x, xn_hi, xn_lo, cn_hi, cn_lo, diag);
  hipLaunchKernelGGL(k2_mfma, dim3(NRB * NCB), dim3(256), 0, stream,
                     (const unsigned short*)xn_hi, (const unsigned short*)xn_lo,
                     (const unsigned short*)cn_hi, (const unsigned short*)cn_lo,
                     diag, w, b, part);
  hipLaunchKernelGGL(k3_rows, dim3(NG / 256), dim3(256), 0, stream, part, rlp, rcr);
  hipLaunchKernelGGL(k4_reduce, dim3(1), dim3(256), 0, stream, rlp, rcr, out);
}

// Round 4
// 204.453 us; speedup vs baseline: 5.7790x; 1.2047x over previous
//
#include <hip/hip_runtime.h>
#include <math.h>

#define NSPK 2048
#define GUT  10
#define DIM  512
#define NG   (NSPK*GUT)

#define BM 128
#define BN 128
#define BK 128
#define NCB (NSPK/BN)   // 16 column blocks
#define NHB (NCB*2)     // 32 column half-blocks (64 cols each) -- one per wave
#define NRB (NG/BM)     // 160 row blocks

typedef __attribute__((ext_vector_type(4))) int   int4v;
typedef __attribute__((ext_vector_type(4))) float f32x4;

#define QMAX 32512.0f   // 127*256 + 127 -> h,l both fit int8

__device__ inline void gload_lds16(const void* g, void* l) {
  __builtin_amdgcn_global_load_lds(
      (const __attribute__((address_space(1))) void*)g,
      (__attribute__((address_space(3))) void*)l, 16, 0, 0);
}

__device__ inline void split16(float v, float qs, int& h, int& l) {
  const int q = (int)rintf(v * qs);            // |q| <= 32512
  h = (q + 128) >> 8;                          // round(q/256), in [-127,127]
  l = q - (h << 8);                            // in [-128,127]
}

// ---------------- Kernel 1: per-speaker prep (+ i8 h/l emit + scales) ----------------
__global__ __launch_bounds__(256) void k1_prep(const float* __restrict__ x,
    unsigned short* __restrict__ xn_h, unsigned short* __restrict__ xn_l,
    unsigned short* __restrict__ cn_h, unsigned short* __restrict__ cn_l,
    float* __restrict__ xs, float* __restrict__ cs, float* __restrict__ diag)
{
  const int n = blockIdx.x;
  const int t = threadIdx.x;
  const float* xb = x + (size_t)n * GUT * DIM + 2 * t;

  float2 xv[GUT];
#pragma unroll
  for (int g = 0; g < GUT; ++g)
    xv[g] = *reinterpret_cast<const float2*>(xb + g * DIM);

  float sx = 0.f, sy = 0.f;
#pragma unroll
  for (int g = 0; g < GUT; ++g) { sx += xv[g].x; sy += xv[g].y; }

  float part[21], pm[11];
#pragma unroll
  for (int g = 0; g < GUT; ++g) {
    part[g]      = xv[g].x * xv[g].x + xv[g].y * xv[g].y;
    part[10 + g] = xv[g].x * sx + xv[g].y * sy;
    pm[g]        = fmaxf(fabsf(xv[g].x), fabsf(xv[g].y));
  }
  part[20] = sx * sx + sy * sy;
  pm[10]   = fmaxf(fabsf(sx), fabsf(sy));

  __shared__ float wred[21][4], wred2[11][4];
  __shared__ float res[21], res2[11];
  const int lane = t & 63, wid = t >> 6;
#pragma unroll
  for (int q = 0; q < 21; ++q) {
    float v = part[q];
    for (int off = 32; off > 0; off >>= 1) v += __shfl_down(v, off);
    if (lane == 0) wred[q][wid] = v;
  }
#pragma unroll
  for (int q = 0; q < 11; ++q) {
    float v = pm[q];
    for (int off = 32; off > 0; off >>= 1) v = fmaxf(v, __shfl_down(v, off));
    if (lane == 0) wred2[q][wid] = v;
  }
  __syncthreads();
  if (t < 21) res[t] = wred[t][0] + wred[t][1] + wred[t][2] + wred[t][3];
  if (t < 11) res2[t] = fmaxf(fmaxf(wred2[t][0], wred2[t][1]), fmaxf(wred2[t][2], wred2[t][3]));
  __syncthreads();

  const float psum = res[20];
  // ---- centroid: quantize normalized centroid = sum / max(||sum||, G*eps) ----
  {
    const float csummax = res2[10];
    const float cnorm = sqrtf(psum) * (1.0f / GUT);
    const float cscale = (1.0f / GUT) / fmaxf(cnorm, 1e-8f);   // c_i = sum_i * cscale
    const float qs = QMAX / csummax;
    int h0, l0, h1, l1;
    split16(sx, qs, h0, l0);
    split16(sy, qs, h1, l1);
    cn_h[n * (DIM / 2) + t] = (unsigned short)(((unsigned)(unsigned char)h1 << 8) | (unsigned char)h0);
    cn_l[n * (DIM / 2) + t] = (unsigned short)(((unsigned)(unsigned char)l1 << 8) | (unsigned char)l0);
    if (t == 0) cs[n] = cscale * csummax * (1.0f / QMAX);
  }

  // ---- rows: quantize normalized embeddings ----
#pragma unroll
  for (int g = 0; g < GUT; ++g) {
    const float rowmax = res2[g];
    const float sc = 1.0f / fmaxf(sqrtf(res[g]), 1e-8f);       // xn_i = x_i * sc
    const float qs = QMAX / rowmax;
    int h0, l0, h1, l1;
    split16(xv[g].x, qs, h0, l0);
    split16(xv[g].y, qs, h1, l1);
    const size_t row = (size_t)n * GUT + g;
    xn_h[row * (DIM / 2) + t] = (unsigned short)(((unsigned)(unsigned char)h1 << 8) | (unsigned char)h0);
    xn_l[row * (DIM / 2) + t] = (unsigned short)(((unsigned)(unsigned char)l1 << 8) | (unsigned char)l0);
    if (t == 0) xs[row] = sc * rowmax * (1.0f / QMAX);
  }

  if (t < GUT) {
    const int g = t;
    const float psq = res[g], pd = res[10 + g];
    const float dxe = (pd - psq) * (1.0f / (GUT - 1));
    float ne2 = (psum - 2.f * pd + psq) * (1.0f / ((GUT - 1) * (GUT - 1)));
    ne2 = fmaxf(ne2, 0.f);
    const float dnm = fmaxf(sqrtf(psq), 1e-8f) * fmaxf(sqrtf(ne2), 1e-8f);
    diag[n * GUT + g] = dxe / dnm;
  }
}

// ---------------- Kernel 2: i8 split MFMA GEMM + fused online softmax ----------------
// sim = xs[row]*cs[col]*(65536*hh + 256*(hl+lh)); l*l term dropped (~2.5e-6 err).
// Grid: 160 rowblocks x 16 colblocks. Block: 256 thr = 4 waves, each wave 64x64 out.
// LDS: Ah,Al,Bh,Bl tiles [128][128] i8 (16KB each), XOR-swizzled 16B chunks.
__global__ __launch_bounds__(256, 2) void k2_mfma(
    const unsigned char* __restrict__ xn_h, const unsigned char* __restrict__ xn_l,
    const unsigned char* __restrict__ cn_h, const unsigned char* __restrict__ cn_l,
    const float* __restrict__ xs, const float* __restrict__ cs,
    const float* __restrict__ diag, const float* __restrict__ wp,
    const float* __restrict__ bp, float* __restrict__ partial)
{
  __shared__ char ldsb[4 * BM * BK];          // 64 KB
  const int AH = 0, AL = 16384, BH = 32768, BL = 49152;

  const int tid = threadIdx.x;
  const int l = tid & 63, w = tid >> 6;
  const int rb = blockIdx.x >> 4, cb = blockIdx.x & 15;
  const int rowbase = rb * BM, colbase = cb * BN;

  int4v acc1[4][4], acc2[4][4];
#pragma unroll
  for (int i = 0; i < 4; ++i)
#pragma unroll
    for (int j = 0; j < 4; ++j)
#pragma unroll
      for (int e = 0; e < 4; ++e) { acc1[i][j][e] = 0; acc2[i][j][e] = 0; }

  // Staging: instr i covers LDS rows i*8..i*8+7 (1024B); lane l -> row i*8+(l>>3),
  // 16B chunk (l&7). Pre-swizzled global chunk = (l&7)^(l>>3)  [rule 21].
  const int sR = l >> 3;
  const int sC = (l & 7) ^ sR;
  const int srcColByte = sC * 16;

  const int wr = w >> 1, wc = w & 1;
  const int lr = l & 15, lq = l >> 4, axor = l & 7;
  int aOff[4], bOff[4];
#pragma unroll
  for (int f = 0; f < 4; ++f) {
    aOff[f] = (wr * 64 + f * 16 + lr) * BK;    // byte offset of row (128B rows)
    bOff[f] = (wc * 64 + f * 16 + lr) * BK;
  }

  for (int kc = 0; kc < DIM / BK; ++kc) {      // 4 iterations
    __syncthreads();
#pragma unroll
    for (int q = 0; q < 4; ++q) {
      const int i = w * 4 + q;
      const size_t aoff = (size_t)(rowbase + i * 8 + sR) * DIM + kc * BK + srcColByte;
      const size_t boff = (size_t)(colbase + i * 8 + sR) * DIM + kc * BK + srcColByte;
      gload_lds16(xn_h + aoff, ldsb + AH + i * 1024);
      gload_lds16(xn_l + aoff, ldsb + AL + i * 1024);
      gload_lds16(cn_h + boff, ldsb + BH + i * 1024);
      gload_lds16(cn_l + boff, ldsb + BL + i * 1024);
    }
    __syncthreads();

#pragma unroll
    for (int kk = 0; kk < 2; ++kk) {           // two K=64 slabs
      const int coff = ((kk * 4 + lq) ^ axor) * 16;
      int4v ah[4], al4[4], bh[4], bl4[4];
#pragma unroll
      for (int f = 0; f < 4; ++f) {
        ah[f]  = *reinterpret_cast<const int4v*>(ldsb + AH + aOff[f] + coff);
        al4[f] = *reinterpret_cast<const int4v*>(ldsb + AL + aOff[f] + coff);
        bh[f]  = *reinterpret_cast<const int4v*>(ldsb + BH + bOff[f] + coff);
        bl4[f] = *reinterpret_cast<const int4v*>(ldsb + BL + bOff[f] + coff);
      }
#pragma unroll
      for (int mf = 0; mf < 4; ++mf)
#pragma unroll
        for (int nf = 0; nf < 4; ++nf) {
          acc1[mf][nf] = __builtin_amdgcn_mfma_i32_16x16x64_i8(ah[mf], bh[nf], acc1[mf][nf], 0, 0, 0);
          acc2[mf][nf] = __builtin_amdgcn_mfma_i32_16x16x64_i8(ah[mf], bl4[nf], acc2[mf][nf], 0, 0, 0);
          acc2[mf][nf] = __builtin_amdgcn_mfma_i32_16x16x64_i8(al4[mf], bh[nf], acc2[mf][nf], 0, 0, 0);
        }
    }
  }

  // ---- epilogue: C/D layout col=lane&15, row=(lane>>4)*4+reg ----
  const float wv = wp[0], bv = bp[0];
  float cs4[4];
#pragma unroll
  for (int nf = 0; nf < 4; ++nf)
    cs4[nf] = cs[colbase + wc * 64 + nf * 16 + lr];

#pragma unroll
  for (int mf = 0; mf < 4; ++mf) {
#pragma unroll
    for (int r = 0; r < 4; ++r) {
      const int row = rowbase + wr * 64 + mf * 16 + lq * 4 + r;
      const int n = row / GUT;
      const int tcol = n - colbase;
      const float dval = (tcol >= 0 && tcol < BN) ? diag[row] : 0.f;
      const float xsr = xs[row];
      float mx = -__builtin_inff(), se = 0.f;
      float bvv = -__builtin_inff(), tg = -__builtin_inff();
      int bi = 0x7fffffff;
#pragma unroll
      for (int nf = 0; nf < 4; ++nf) {
        const int coll = wc * 64 + nf * 16 + lr;
        float s = xsr * cs4[nf] *
                  (65536.0f * (float)acc1[mf][nf][r] + 256.0f * (float)acc2[mf][nf][r]);
        if (coll == tcol) s = dval;
        s = fmaxf(s, 1e-6f);
        const float L = fmaf(s, wv, bv);
        if (coll == tcol) tg = L;
        if (L > bvv) { bvv = L; bi = colbase + coll; }
        if (L > mx) { se = se * __expf(mx - L) + 1.0f; mx = L; }
        else          se += __expf(L - mx);
      }
#pragma unroll
      for (int off = 1; off < 16; off <<= 1) {
        const float omx = __shfl_xor(mx, off);
        const float ose = __shfl_xor(se, off);
        const float obv = __shfl_xor(bvv, off);
        const int   obi = __shfl_xor(bi, off);
        const float otg = __shfl_xor(tg, off);
        const float nm = fmaxf(mx, omx);
        se = se * __expf(mx - nm) + ose * __expf(omx - nm);
        mx = nm;
        if (obv > bvv || (obv == bvv && obi < bi)) { bvv = obv; bi = obi; }
        tg = fmaxf(tg, otg);
      }
      if (lr == 0) {
        float* p = partial + ((size_t)row * NHB + cb * 2 + wc) * 5;
        p[0] = mx; p[1] = se; p[2] = bvv; p[3] = __int_as_float(bi); p[4] = tg;
      }
    }
  }
}

// ---------------- Kernel 3: merge 32 half-block partials per row ----------------
__global__ __launch_bounds__(256) void k3_rows(const float* __restrict__ partial,
    float* __restrict__ rlp, float* __restrict__ rcr)
{
  const int row = blockIdx.x * 256 + threadIdx.x;
  const float* p = partial + (size_t)row * NHB * 5;
  float mx = -__builtin_inff(), se = 0.f, bv = -__builtin_inff(), tg = -__builtin_inff();
  int bi = 0x7fffffff;
#pragma unroll
  for (int c = 0; c < NHB; ++c) {
    const float m2 = p[c * 5 + 0], s2 = p[c * 5 + 1], b2 = p[c * 5 + 2];
    const int   i2 = __float_as_int(p[c * 5 + 3]);
    const float t2 = p[c * 5 + 4];
    const float nm = fmaxf(mx, m2);
    se = se * __expf(mx - nm) + s2 * __expf(m2 - nm);
    mx = nm;
    if (b2 > bv || (b2 == bv && i2 < bi)) { bv = b2; bi = i2; }
    tg = fmaxf(tg, t2);
  }
  rlp[row] = tg - mx - logf(se);
  rcr[row] = (bi == row / GUT) ? 1.0f : 0.0f;
}

// ---------------- Kernel 4: final scalar reduction ----------------
__global__ __launch_bounds__(256) void k4_reduce(const float* __restrict__ row_logp,
    const float* __restrict__ row_corr, float* __restrict__ out)
{
  const int t = threadIdx.x;
  float sl = 0.f, sc = 0.f;
  for (int i = t; i < NG; i += 256) { sl += row_logp[i]; sc += row_corr[i]; }
  for (int off = 32; off > 0; off >>= 1) { sl += __shfl_down(sl, off); sc += __shfl_down(sc, off); }
  __shared__ float ra[4], rb2[4];
  const int lane = t & 63, wid = t >> 6;
  if (lane == 0) { ra[wid] = sl; rb2[wid] = sc; }
  __syncthreads();
  if (t == 0) {
    const float S = ra[0] + ra[1] + ra[2] + ra[3];
    const float C = rb2[0] + rb2[1] + rb2[2] + rb2[3];
    out[0] = -(S * (1.0f / NG));
    out[1] = C * (100.0f / NG);
  }
}

extern "C" void kernel_launch(void* const* d_in, const int* in_sizes, int n_in,
                              void* d_out, int out_size, void* d_ws, size_t ws_size,
                              hipStream_t stream)
{
  const float* x = (const float*)d_in[0];
  const float* w = (const float*)d_in[1];
  const float* b = (const float*)d_in[2];
  float* out = (float*)d_out;

  char* ws = (char*)d_ws;
  unsigned short* xn_h = (unsigned short*)ws;                         // NG*512 i8
  unsigned short* xn_l = (unsigned short*)(ws + (size_t)NG * DIM);    // NG*512 i8
  unsigned short* cn_h = (unsigned short*)(ws + (size_t)NG * DIM * 2);            // NSPK*512 i8
  unsigned short* cn_l = (unsigned short*)(ws + (size_t)NG * DIM * 2 + (size_t)NSPK * DIM);
  char* after = ws + (size_t)NG * DIM * 2 + (size_t)NSPK * DIM * 2;
  float* xs   = (float*)after;                                        // NG
  float* cs   = xs + NG;                                              // NSPK
  float* diag = cs + NSPK;                                            // NG
  float* part = diag + NG;                                            // NG*32*5
  float* rlp  = part + (size_t)NG * NHB * 5;                          // NG
  float* rcr  = rlp + NG;                                             // NG

  hipLaunchKernelGGL(k1_prep, dim3(NSPK), dim3(256), 0, stream,
                     x, xn_h, xn_l, cn_h, cn_l, xs, cs, diag);
  hipLaunchKernelGGL(k2_mfma, dim3(NRB * NCB), dim3(256), 0, stream,
                     (const unsigned char*)xn_h, (const unsigned char*)xn_l,
                     (const unsigned char*)cn_h, (const unsigned char*)cn_l,
                     xs, cs, diag, w, b, part);
  hipLaunchKernelGGL(k3_rows, dim3(NG / 256), dim3(256), 0, stream, part, rlp, rcr);
  hipLaunchKernelGGL(k4_reduce, dim3(1), dim3(256), 0, stream, rlp, rcr, out);
}

// Round 5
// 171.422 us; speedup vs baseline: 6.8925x; 1.1927x over previous
//
#include <hip/hip_runtime.h>
#include <math.h>

#define NSPK 2048
#define GUT  10
#define DIM  512
#define NG   (NSPK*GUT)

#define BM 128
#define BN 128
#define BK 64
#define NCB (NSPK/BN)   // 16 column blocks
#define NHB (NCB*2)     // 32 column half-blocks (64 cols each) -- one per wave
#define NRB (NG/BM)     // 160 row blocks
#define NKC (DIM/BK)    // 8 K-iterations

typedef __attribute__((ext_vector_type(4))) int   int4v;
typedef __attribute__((ext_vector_type(4))) float f32x4;

#define QMAX 32512.0f   // 127*256 + 127 -> h,l both fit int8

__device__ inline void gload_lds16(const void* g, void* l) {
  __builtin_amdgcn_global_load_lds(
      (const __attribute__((address_space(1))) void*)g,
      (__attribute__((address_space(3))) void*)l, 16, 0, 0);
}

__device__ inline void split16(float v, float qs, int& h, int& l) {
  const int q = (int)rintf(v * qs);            // |q| <= 32512
  h = (q + 128) >> 8;                          // round(q/256), in [-127,127]
  l = q - (h << 8);                            // in [-128,127]
}

// ---------------- Kernel 1: per-speaker prep (+ i8 h/l emit + scales) ----------------
__global__ __launch_bounds__(256) void k1_prep(const float* __restrict__ x,
    unsigned short* __restrict__ xn_h, unsigned short* __restrict__ xn_l,
    unsigned short* __restrict__ cn_h, unsigned short* __restrict__ cn_l,
    float* __restrict__ xs, float* __restrict__ cs, float* __restrict__ diag)
{
  const int n = blockIdx.x;
  const int t = threadIdx.x;
  const float* xb = x + (size_t)n * GUT * DIM + 2 * t;

  float2 xv[GUT];
#pragma unroll
  for (int g = 0; g < GUT; ++g)
    xv[g] = *reinterpret_cast<const float2*>(xb + g * DIM);

  float sx = 0.f, sy = 0.f;
#pragma unroll
  for (int g = 0; g < GUT; ++g) { sx += xv[g].x; sy += xv[g].y; }

  float part[21], pm[11];
#pragma unroll
  for (int g = 0; g < GUT; ++g) {
    part[g]      = xv[g].x * xv[g].x + xv[g].y * xv[g].y;
    part[10 + g] = xv[g].x * sx + xv[g].y * sy;
    pm[g]        = fmaxf(fabsf(xv[g].x), fabsf(xv[g].y));
  }
  part[20] = sx * sx + sy * sy;
  pm[10]   = fmaxf(fabsf(sx), fabsf(sy));

  __shared__ float wred[21][4], wred2[11][4];
  __shared__ float res[21], res2[11];
  const int lane = t & 63, wid = t >> 6;
#pragma unroll
  for (int q = 0; q < 21; ++q) {
    float v = part[q];
    for (int off = 32; off > 0; off >>= 1) v += __shfl_down(v, off);
    if (lane == 0) wred[q][wid] = v;
  }
#pragma unroll
  for (int q = 0; q < 11; ++q) {
    float v = pm[q];
    for (int off = 32; off > 0; off >>= 1) v = fmaxf(v, __shfl_down(v, off));
    if (lane == 0) wred2[q][wid] = v;
  }
  __syncthreads();
  if (t < 21) res[t] = wred[t][0] + wred[t][1] + wred[t][2] + wred[t][3];
  if (t < 11) res2[t] = fmaxf(fmaxf(wred2[t][0], wred2[t][1]), fmaxf(wred2[t][2], wred2[t][3]));
  __syncthreads();

  const float psum = res[20];
  {
    const float csummax = res2[10];
    const float cnorm = sqrtf(psum) * (1.0f / GUT);
    const float cscale = (1.0f / GUT) / fmaxf(cnorm, 1e-8f);   // c_i = sum_i * cscale
    const float qs = QMAX / csummax;
    int h0, l0, h1, l1;
    split16(sx, qs, h0, l0);
    split16(sy, qs, h1, l1);
    cn_h[n * (DIM / 2) + t] = (unsigned short)(((unsigned)(unsigned char)h1 << 8) | (unsigned char)h0);
    cn_l[n * (DIM / 2) + t] = (unsigned short)(((unsigned)(unsigned char)l1 << 8) | (unsigned char)l0);
    if (t == 0) cs[n] = cscale * csummax * (1.0f / QMAX);
  }

#pragma unroll
  for (int g = 0; g < GUT; ++g) {
    const float rowmax = res2[g];
    const float sc = 1.0f / fmaxf(sqrtf(res[g]), 1e-8f);       // xn_i = x_i * sc
    const float qs = QMAX / rowmax;
    int h0, l0, h1, l1;
    split16(xv[g].x, qs, h0, l0);
    split16(xv[g].y, qs, h1, l1);
    const size_t row = (size_t)n * GUT + g;
    xn_h[row * (DIM / 2) + t] = (unsigned short)(((unsigned)(unsigned char)h1 << 8) | (unsigned char)h0);
    xn_l[row * (DIM / 2) + t] = (unsigned short)(((unsigned)(unsigned char)l1 << 8) | (unsigned char)l0);
    if (t == 0) xs[row] = sc * rowmax * (1.0f / QMAX);
  }

  if (t < GUT) {
    const int g = t;
    const float psq = res[g], pd = res[10 + g];
    const float dxe = (pd - psq) * (1.0f / (GUT - 1));
    float ne2 = (psum - 2.f * pd + psq) * (1.0f / ((GUT - 1) * (GUT - 1)));
    ne2 = fmaxf(ne2, 0.f);
    const float dnm = fmaxf(sqrtf(psq), 1e-8f) * fmaxf(sqrtf(ne2), 1e-8f);
    diag[n * GUT + g] = dxe / dnm;
  }
}

// ---------------- Kernel 2: i8 split MFMA GEMM, 2-deep pipelined, fixed-max softmax ----------------
// sim = xs[row]*cs[col]*256*(256*hh + (hl+lh)); l*l term dropped (~2.5e-6 err).
// BK=64, LDS double-buffered (2x32KB). Per iter: STAGE(next) -> vmcnt(8) -> barrier
// -> ds_read+MFMA -> lgkmcnt(0)+barrier. Counted vmcnt keeps prefetch in flight.
__global__ __launch_bounds__(256, 2) void k2_mfma(
    const unsigned char* __restrict__ xn_h, const unsigned char* __restrict__ xn_l,
    const unsigned char* __restrict__ cn_h, const unsigned char* __restrict__ cn_l,
    const float* __restrict__ xs, const float* __restrict__ cs,
    const float* __restrict__ diag, const float* __restrict__ wp,
    const float* __restrict__ bp, float* __restrict__ partial)
{
  __shared__ char ldsb[2 * 32768];            // 64 KB: 2 bufs x {AH,AL,BH,BL}[128][64]

  const int tid = threadIdx.x;
  const int l = tid & 63, w = tid >> 6;
  const int rb = blockIdx.x >> 4, cb = blockIdx.x & 15;
  const int rowbase = rb * BM, colbase = cb * BN;

  int4v acc1[4][4], acc2[4][4];
#pragma unroll
  for (int i = 0; i < 4; ++i)
#pragma unroll
    for (int j = 0; j < 4; ++j)
#pragma unroll
      for (int e = 0; e < 4; ++e) { acc1[i][j][e] = 0; acc2[i][j][e] = 0; }

  // Staging: each 1024B instr covers 16 rows (64B/row); lane l -> row i*16+(l>>2),
  // LDS chunk (l&3). Pre-swizzled global chunk = (l&3)^((l>>2)&3)  [rule 21].
  const int sR = l >> 2;
  const int sC16 = (((l & 3) ^ (sR & 3)) << 4);

  // Fragment reads: row = 16f+lr, k-chunk lq; swizzled chunk = lq^(lr&3).
  const int wr = w >> 1, wc = w & 1;
  const int lr = l & 15, lq = l >> 4;
  int aRel[4], bRel[4];
#pragma unroll
  for (int f = 0; f < 4; ++f) {
    aRel[f] = ((wr * 64 + f * 16 + lr) << 6) + ((lq ^ (lr & 3)) << 4);
    bRel[f] = ((wc * 64 + f * 16 + lr) << 6) + ((lq ^ (lr & 3)) << 4);
  }

#define STAGE(buf, kcn) do {                                                   \
    char* dst_ = ldsb + (buf) * 32768;                                         \
    _Pragma("unroll")                                                          \
    for (int q_ = 0; q_ < 2; ++q_) {                                           \
      const int i_ = w * 2 + q_;                                               \
      const size_t ao_ = (size_t)(rowbase + i_ * 16 + sR) * DIM + (kcn) * BK + sC16; \
      const size_t bo_ = (size_t)(colbase + i_ * 16 + sR) * DIM + (kcn) * BK + sC16; \
      gload_lds16(xn_h + ao_, dst_ +     0 + i_ * 1024);                       \
      gload_lds16(xn_l + ao_, dst_ +  8192 + i_ * 1024);                       \
      gload_lds16(cn_h + bo_, dst_ + 16384 + i_ * 1024);                       \
      gload_lds16(cn_l + bo_, dst_ + 24576 + i_ * 1024);                       \
    }                                                                          \
  } while (0)

  STAGE(0, 0);

  for (int kc = 0; kc < NKC; ++kc) {
    const int cur = kc & 1;
    if (kc < NKC - 1) {
      STAGE(cur ^ 1, kc + 1);
      asm volatile("s_waitcnt vmcnt(8)" ::: "memory");   // cur's 8 loads done; next 8 in flight
    } else {
      asm volatile("s_waitcnt vmcnt(0)" ::: "memory");
    }
    __builtin_amdgcn_s_barrier();

    const char* base = ldsb + cur * 32768;
    int4v ah[4], al4[4], bh4[4], bl4[4];
#pragma unroll
    for (int f = 0; f < 4; ++f) {
      ah[f]  = *reinterpret_cast<const int4v*>(base +     0 + aRel[f]);
      al4[f] = *reinterpret_cast<const int4v*>(base +  8192 + aRel[f]);
      bh4[f] = *reinterpret_cast<const int4v*>(base + 16384 + bRel[f]);
      bl4[f] = *reinterpret_cast<const int4v*>(base + 24576 + bRel[f]);
    }
#pragma unroll
    for (int mf = 0; mf < 4; ++mf)
#pragma unroll
      for (int nf = 0; nf < 4; ++nf) {
        acc1[mf][nf] = __builtin_amdgcn_mfma_i32_16x16x64_i8(ah[mf], bh4[nf], acc1[mf][nf], 0, 0, 0);
        acc2[mf][nf] = __builtin_amdgcn_mfma_i32_16x16x64_i8(ah[mf], bl4[nf], acc2[mf][nf], 0, 0, 0);
        acc2[mf][nf] = __builtin_amdgcn_mfma_i32_16x16x64_i8(al4[mf], bh4[nf], acc2[mf][nf], 0, 0, 0);
      }

    if (kc < NKC - 1) {
      asm volatile("s_waitcnt lgkmcnt(0)" ::: "memory"); // reads complete before buf reuse
      __builtin_amdgcn_s_barrier();
    }
  }
#undef STAGE

  // ---- epilogue: fixed-max softmax. C/D layout col=lane&15, row=(lane>>4)*4+reg ----
  const float wv = wp[0], bvb = bp[0];
  const float MFIX = fabsf(wv) + bvb;                    // upper bound on logits
  float xc4[4];
#pragma unroll
  for (int nf = 0; nf < 4; ++nf)
    xc4[nf] = cs[colbase + wc * 64 + nf * 16 + lr] * 256.0f;

#pragma unroll
  for (int mf = 0; mf < 4; ++mf) {
#pragma unroll
    for (int r = 0; r < 4; ++r) {
      const int row = rowbase + wr * 64 + mf * 16 + lq * 4 + r;
      const int n = row / GUT;
      const int tcol = n - colbase;
      const float dval = (tcol >= 0 && tcol < BN) ? diag[row] : 0.f;
      const float xsr = xs[row];
      float se = 0.f, bvv = -__builtin_inff(), tg = -__builtin_inff();
      int bi = 0x7fffffff;
#pragma unroll
      for (int nf = 0; nf < 4; ++nf) {
        const int coll = wc * 64 + nf * 16 + lr;
        float s = (xsr * xc4[nf]) *
                  fmaf(256.0f, (float)acc1[mf][nf][r], (float)acc2[mf][nf][r]);
        if (coll == tcol) s = dval;
        s = fmaxf(s, 1e-6f);
        const float L = fmaf(s, wv, bvb);
        se += __expf(L - MFIX);
        tg = (coll == tcol) ? L : tg;
        if (L > bvv) { bvv = L; bi = colbase + coll; }
      }
#pragma unroll
      for (int off = 1; off < 16; off <<= 1) {
        se += __shfl_xor(se, off);
        const float obv = __shfl_xor(bvv, off);
        const int   obi = __shfl_xor(bi, off);
        tg = fmaxf(tg, __shfl_xor(tg, off));
        if (obv > bvv || (obv == bvv && obi < bi)) { bvv = obv; bi = obi; }
      }
      if (lr == 0) {
        f32x4 slot;
        slot[0] = se; slot[1] = bvv; slot[2] = __int_as_float(bi); slot[3] = tg;
        *reinterpret_cast<f32x4*>(partial + ((size_t)row * NHB + cb * 2 + wc) * 4) = slot;
      }
    }
  }
}

// ---------------- Kernel 3: merge 32 half-block partials per row (pure sums) ----------------
__global__ __launch_bounds__(256) void k3_rows(const float* __restrict__ partial,
    const float* __restrict__ wp, const float* __restrict__ bp,
    float* __restrict__ rlp, float* __restrict__ rcr)
{
  const int row = blockIdx.x * 256 + threadIdx.x;
  const float MFIX = fabsf(wp[0]) + bp[0];
  const f32x4* p = reinterpret_cast<const f32x4*>(partial + (size_t)row * NHB * 4);
  float se = 0.f, bv = -__builtin_inff(), tg = -__builtin_inff();
  int bi = 0x7fffffff;
#pragma unroll
  for (int c = 0; c < NHB; ++c) {
    const f32x4 v = p[c];
    se += v[0];
    const int i2 = __float_as_int(v[2]);
    if (v[1] > bv || (v[1] == bv && i2 < bi)) { bv = v[1]; bi = i2; }
    tg = fmaxf(tg, v[3]);
  }
  rlp[row] = tg - MFIX - logf(se);
  rcr[row] = (bi == row / GUT) ? 1.0f : 0.0f;
}

// ---------------- Kernel 4: final scalar reduction ----------------
__global__ __launch_bounds__(256) void k4_reduce(const float* __restrict__ row_logp,
    const float* __restrict__ row_corr, float* __restrict__ out)
{
  const int t = threadIdx.x;
  float sl = 0.f, sc = 0.f;
  for (int i = t; i < NG; i += 256) { sl += row_logp[i]; sc += row_corr[i]; }
  for (int off = 32; off > 0; off >>= 1) { sl += __shfl_down(sl, off); sc += __shfl_down(sc, off); }
  __shared__ float ra[4], rb2[4];
  const int lane = t & 63, wid = t >> 6;
  if (lane == 0) { ra[wid] = sl; rb2[wid] = sc; }
  __syncthreads();
  if (t == 0) {
    const float S = ra[0] + ra[1] + ra[2] + ra[3];
    const float C = rb2[0] + rb2[1] + rb2[2] + rb2[3];
    out[0] = -(S * (1.0f / NG));
    out[1] = C * (100.0f / NG);
  }
}

extern "C" void kernel_launch(void* const* d_in, const int* in_sizes, int n_in,
                              void* d_out, int out_size, void* d_ws, size_t ws_size,
                              hipStream_t stream)
{
  const float* x = (const float*)d_in[0];
  const float* w = (const float*)d_in[1];
  const float* b = (const float*)d_in[2];
  float* out = (float*)d_out;

  char* ws = (char*)d_ws;
  unsigned short* xn_h = (unsigned short*)ws;                         // NG*512 i8
  unsigned short* xn_l = (unsigned short*)(ws + (size_t)NG * DIM);    // NG*512 i8
  unsigned short* cn_h = (unsigned short*)(ws + (size_t)NG * DIM * 2);
  unsigned short* cn_l = (unsigned short*)(ws + (size_t)NG * DIM * 2 + (size_t)NSPK * DIM);
  char* after = ws + (size_t)NG * DIM * 2 + (size_t)NSPK * DIM * 2;
  float* xs   = (float*)after;                                        // NG
  float* cs   = xs + NG;                                              // NSPK
  float* diag = cs + NSPK;                                            // NG
  float* part = diag + NG;                                            // NG*32*4
  float* rlp  = part + (size_t)NG * NHB * 4;                          // NG
  float* rcr  = rlp + NG;                                             // NG

  hipLaunchKernelGGL(k1_prep, dim3(NSPK), dim3(256), 0, stream,
                     x, xn_h, xn_l, cn_h, cn_l, xs, cs, diag);
  hipLaunchKernelGGL(k2_mfma, dim3(NRB * NCB), dim3(256), 0, stream,
                     (const unsigned char*)xn_h, (const unsigned char*)xn_l,
                     (const unsigned char*)cn_h, (const unsigned char*)cn_l,
                     xs, cs, diag, w, b, part);
  hipLaunchKernelGGL(k3_rows, dim3(NG / 256), dim3(256), 0, stream, part, w, b, rlp, rcr);
  hipLaunchKernelGGL(k4_reduce, dim3(1), dim3(256), 0, stream, rlp, rcr, out);
}